// Round 1
// baseline (262.222 us; speedup 1.0000x reference)
//
#include <hip/hip_runtime.h>

#define NUM_LABELS 500
#define NB 8
#define NP (1024 * 1024)

// Main binning kernel: per-block LDS histogram of (s, ss, cnt) over 500 labels,
// flushed to global bins with atomics.
__global__ __launch_bounds__(512) void lv_bins(const float* __restrict__ x,
                                               const int* __restrict__ tgt,
                                               float* __restrict__ bins,
                                               int blocksPerBatch) {
    __shared__ float s_s[NUM_LABELS];
    __shared__ float s_q[NUM_LABELS];
    __shared__ float s_c[NUM_LABELS];

    const int b = blockIdx.y;
    for (int i = threadIdx.x; i < NUM_LABELS; i += blockDim.x) {
        s_s[i] = 0.f; s_q[i] = 0.f; s_c[i] = 0.f;
    }
    __syncthreads();

    const float* x0 = x + (size_t)(b * 3 + 0) * NP;
    const float* x1 = x + (size_t)(b * 3 + 1) * NP;
    const float* x2 = x + (size_t)(b * 3 + 2) * NP;
    const int*   tg = tgt + (size_t)b * NP;

    const int pixPerBlock = NP / blocksPerBatch;
    const int p0 = blockIdx.x * pixPerBlock;
    const int pend = p0 + pixPerBlock;

    for (int p = p0 + (int)threadIdx.x * 4; p < pend; p += (int)blockDim.x * 4) {
        const int4   t4 = *(const int4*)(tg + p);
        const float4 a4 = *(const float4*)(x0 + p);
        const float4 b4 = *(const float4*)(x1 + p);
        const float4 c4 = *(const float4*)(x2 + p);

        if (t4.x > 0) {
            float v = a4.x + b4.x + c4.x;
            float q = a4.x * a4.x + b4.x * b4.x + c4.x * c4.x;
            atomicAdd(&s_s[t4.x], v); atomicAdd(&s_q[t4.x], q); atomicAdd(&s_c[t4.x], 1.f);
        }
        if (t4.y > 0) {
            float v = a4.y + b4.y + c4.y;
            float q = a4.y * a4.y + b4.y * b4.y + c4.y * c4.y;
            atomicAdd(&s_s[t4.y], v); atomicAdd(&s_q[t4.y], q); atomicAdd(&s_c[t4.y], 1.f);
        }
        if (t4.z > 0) {
            float v = a4.z + b4.z + c4.z;
            float q = a4.z * a4.z + b4.z * b4.z + c4.z * c4.z;
            atomicAdd(&s_s[t4.z], v); atomicAdd(&s_q[t4.z], q); atomicAdd(&s_c[t4.z], 1.f);
        }
        if (t4.w > 0) {
            float v = a4.w + b4.w + c4.w;
            float q = a4.w * a4.w + b4.w * b4.w + c4.w * c4.w;
            atomicAdd(&s_s[t4.w], v); atomicAdd(&s_q[t4.w], q); atomicAdd(&s_c[t4.w], 1.f);
        }
    }

    __syncthreads();

    float* g_s = bins;
    float* g_q = bins + NB * NUM_LABELS;
    float* g_c = bins + 2 * NB * NUM_LABELS;
    for (int i = threadIdx.x; i < NUM_LABELS; i += blockDim.x) {
        float c = s_c[i];
        if (c != 0.f) {
            atomicAdd(&g_s[b * NUM_LABELS + i], s_s[i]);
            atomicAdd(&g_q[b * NUM_LABELS + i], s_q[i]);
            atomicAdd(&g_c[b * NUM_LABELS + i], c);
        }
    }
}

// Finalize: 8 waves, wave b reduces batch b over labels 1..499.
__global__ __launch_bounds__(512) void lv_final(const float* __restrict__ bins,
                                                float* __restrict__ out) {
    const int wave = threadIdx.x >> 6;
    const int lane = threadIdx.x & 63;

    const float* g_s = bins;
    const float* g_q = bins + NB * NUM_LABELS;
    const float* g_c = bins + 2 * NB * NUM_LABELS;

    float var_sum = 0.f;
    float uniq = 0.f;
    for (int l = 1 + lane; l < NUM_LABELS; l += 64) {
        float c = g_c[wave * NUM_LABELS + l];
        float s = g_s[wave * NUM_LABELS + l];
        float q = g_q[wave * NUM_LABELS + l];
        if (c > 0.f) uniq += 1.f;
        if (c > 1.f) {
            float N = 3.f * c;
            var_sum += (q - s * s / N) / (N - 1.f);
        }
    }
    for (int off = 32; off > 0; off >>= 1) {
        var_sum += __shfl_down(var_sum, off);
        uniq    += __shfl_down(uniq, off);
    }

    __shared__ float part[NB];
    if (lane == 0) part[wave] = var_sum / (uniq + 1e-8f);
    __syncthreads();

    if (threadIdx.x == 0) {
        float acc = 0.f;
        for (int i = 0; i < NB; ++i) acc += part[i];
        out[0] = acc * (1.f / NB);
    }
}

extern "C" void kernel_launch(void* const* d_in, const int* in_sizes, int n_in,
                              void* d_out, int out_size, void* d_ws, size_t ws_size,
                              hipStream_t stream) {
    const float* x   = (const float*)d_in[0];
    const int*   tgt = (const int*)d_in[1];
    float*       out = (float*)d_out;
    float*       bins = (float*)d_ws;  // 3 * 8 * 500 floats = 48 KB

    hipMemsetAsync(bins, 0, (size_t)3 * NB * NUM_LABELS * sizeof(float), stream);

    const int blocksPerBatch = 64;
    dim3 grid(blocksPerBatch, NB);
    lv_bins<<<grid, 512, 0, stream>>>(x, tgt, bins, blocksPerBatch);
    lv_final<<<1, 512, 0, stream>>>(bins, out);
}

// Round 2
// 178.127 us; speedup vs baseline: 1.4721x; 1.4721x over previous
//
#include <hip/hip_runtime.h>

#define NUM_LABELS 500
#define NB 8
#define NP (1024 * 1024)
#define BPB 128   // blocks per batch
#define TPB 512

// Packed u64 fixed-point accumulator per label:
//   bits [48..63] : count of pixels
//   bits [24..47] : sum of round((v+64)*256), v = sum of 3 channel values
//   bits [0 ..23] : sum of round(q*64), q = sum of 3 channel squares
// One ds_add_u64 per pixel instead of three ds_add_f32.

__device__ __forceinline__ void lv_accum(unsigned long long* h, int t,
                                         float a, float b, float c) {
    if (t > 0) {
        float v = a + b + c;
        float q = a * a + b * b + c * c;
        unsigned vf = (unsigned)(fmaf(v, 256.f, 16384.5f));  // (v+64)*256, rounded
        unsigned qf = (unsigned)(fmaf(q, 64.f, 0.5f));       // q*64, rounded
        unsigned long long pk =
            (1ULL << 48) | ((unsigned long long)vf << 24) | (unsigned long long)qf;
        atomicAdd(&h[t], pk);
    }
}

__global__ __launch_bounds__(TPB) void lv_bins(const float* __restrict__ x,
                                               const int* __restrict__ tgt,
                                               float* __restrict__ bins) {
    __shared__ unsigned long long h[NUM_LABELS];

    const int b = blockIdx.y;
    for (int i = threadIdx.x; i < NUM_LABELS; i += TPB) h[i] = 0ULL;
    __syncthreads();

    const float* x0 = x + (size_t)(b * 3 + 0) * NP;
    const float* x1 = x + (size_t)(b * 3 + 1) * NP;
    const float* x2 = x + (size_t)(b * 3 + 2) * NP;
    const int*   tg = tgt + (size_t)b * NP;

    const int pixPerBlock = NP / BPB;           // 8192
    const int stride = TPB * 4;                 // 2048
    const int nIter = pixPerBlock / stride;     // 4

    int p = blockIdx.x * pixPerBlock + (int)threadIdx.x * 4;

    // software-pipelined: next iteration's loads issue before current atomics
    int4   t4 = *(const int4*)(tg + p);
    float4 a4 = *(const float4*)(x0 + p);
    float4 b4 = *(const float4*)(x1 + p);
    float4 c4 = *(const float4*)(x2 + p);

    for (int it = 0; it < nIter - 1; ++it) {
        const int pn = p + stride;
        int4   tn = *(const int4*)(tg + pn);
        float4 an = *(const float4*)(x0 + pn);
        float4 bn = *(const float4*)(x1 + pn);
        float4 cn = *(const float4*)(x2 + pn);

        lv_accum(h, t4.x, a4.x, b4.x, c4.x);
        lv_accum(h, t4.y, a4.y, b4.y, c4.y);
        lv_accum(h, t4.z, a4.z, b4.z, c4.z);
        lv_accum(h, t4.w, a4.w, b4.w, c4.w);

        t4 = tn; a4 = an; b4 = bn; c4 = cn;
        p = pn;
    }
    lv_accum(h, t4.x, a4.x, b4.x, c4.x);
    lv_accum(h, t4.y, a4.y, b4.y, c4.y);
    lv_accum(h, t4.z, a4.z, b4.z, c4.z);
    lv_accum(h, t4.w, a4.w, b4.w, c4.w);

    __syncthreads();

    float* g_s = bins;
    float* g_q = bins + NB * NUM_LABELS;
    float* g_c = bins + 2 * NB * NUM_LABELS;
    for (int i = threadIdx.x; i < NUM_LABELS; i += TPB) {
        unsigned long long w = h[i];
        if (w != 0ULL) {
            float cnt = (float)(unsigned)(w >> 48);
            float sv  = (float)(unsigned)((w >> 24) & 0xFFFFFFu) * (1.f / 256.f)
                        - 64.f * cnt;
            float sq  = (float)(unsigned)(w & 0xFFFFFFu) * (1.f / 64.f);
            atomicAdd(&g_s[b * NUM_LABELS + i], sv);
            atomicAdd(&g_q[b * NUM_LABELS + i], sq);
            atomicAdd(&g_c[b * NUM_LABELS + i], cnt);
        }
    }
}

// Finalize: 8 waves, wave b reduces batch b over labels 1..499.
__global__ __launch_bounds__(512) void lv_final(const float* __restrict__ bins,
                                                float* __restrict__ out) {
    const int wave = threadIdx.x >> 6;
    const int lane = threadIdx.x & 63;

    const float* g_s = bins;
    const float* g_q = bins + NB * NUM_LABELS;
    const float* g_c = bins + 2 * NB * NUM_LABELS;

    float var_sum = 0.f;
    float uniq = 0.f;
    for (int l = 1 + lane; l < NUM_LABELS; l += 64) {
        float c = g_c[wave * NUM_LABELS + l];
        float s = g_s[wave * NUM_LABELS + l];
        float q = g_q[wave * NUM_LABELS + l];
        if (c > 0.f) uniq += 1.f;
        if (c > 1.f) {
            float N = 3.f * c;
            var_sum += (q - s * s / N) / (N - 1.f);
        }
    }
    for (int off = 32; off > 0; off >>= 1) {
        var_sum += __shfl_down(var_sum, off);
        uniq    += __shfl_down(uniq, off);
    }

    __shared__ float part[NB];
    if (lane == 0) part[wave] = var_sum / (uniq + 1e-8f);
    __syncthreads();

    if (threadIdx.x == 0) {
        float acc = 0.f;
        for (int i = 0; i < NB; ++i) acc += part[i];
        out[0] = acc * (1.f / NB);
    }
}

extern "C" void kernel_launch(void* const* d_in, const int* in_sizes, int n_in,
                              void* d_out, int out_size, void* d_ws, size_t ws_size,
                              hipStream_t stream) {
    const float* x   = (const float*)d_in[0];
    const int*   tgt = (const int*)d_in[1];
    float*       out = (float*)d_out;
    float*       bins = (float*)d_ws;  // 3 * 8 * 500 floats = 48 KB

    hipMemsetAsync(bins, 0, (size_t)3 * NB * NUM_LABELS * sizeof(float), stream);

    dim3 grid(BPB, NB);
    lv_bins<<<grid, TPB, 0, stream>>>(x, tgt, bins);
    lv_final<<<1, 512, 0, stream>>>(bins, out);
}